// Round 1
// baseline (158.423 us; speedup 1.0000x reference)
//
#include <hip/hip_runtime.h>

// Problem constants
#define NB 4      // batch
#define NI 160    // input spatial size (all 3 dims)
#define NO 43     // output spatial size: ceil(160/4)+3
#define NC 3      // channels
#define KS 7      // gaussian kernel size per axis
#define KPAD 3    // (KS-1)/2
#define MT 16     // max stored taps per composite-weight row (true max = 14)
#define CH 8      // i2 rows per chunk in pass A

// Workspace layout:
//  floats  [0 .. 3*NO*MT)                      : wtab[axis][o][tap]
//  ints    at byte 3*NO*MT*4 = 8256            : wstart[3*NO]
//  floats  at byte 16384                       : S[NB][NI][NO][NO][NC]

// ---------------------------------------------------------------------------
// Setup: factor 3D gaussian into per-axis marginals, compose with the
// jax.image.resize (antialias=True, 'linear') triangle weights into a banded
// 43x160 matrix per axis (<=14 taps, stored as 16 with zero pad).
// ---------------------------------------------------------------------------
__global__ void k_setup(const float* __restrict__ kern,
                        float* __restrict__ wtab, int* __restrict__ wstart) {
    __shared__ float g[3 * KS];
    int t = threadIdx.x;
    if (t < 3 * KS) {
        int ax = t / KS, idx = t % KS;
        float s = 0.f;
        for (int a = 0; a < KS; ++a)
            for (int b = 0; b < KS; ++b) {
                int i0 = (ax == 0) ? idx : a;
                int i1 = (ax == 1) ? idx : ((ax == 0) ? a : b);
                int i2 = (ax == 2) ? idx : b;
                s += kern[(i0 * KS + i1) * KS + i2];
            }
        g[t] = s;
    }
    __syncthreads();

    const float inv_scale = (float)NI / (float)NO;   // 160/43
    const float ksc = inv_scale;                     // kernel_scale (antialias)
    for (int row = t; row < 3 * NO; row += blockDim.x) {
        int ax = row / NO, o = row % NO;
        float sf = ((float)o + 0.5f) * inv_scale - 0.5f;   // half-pixel centers
        int ilo = (int)ceilf(sf - ksc);  if (ilo < 0) ilo = 0;
        int ihi = (int)floorf(sf + ksc); if (ihi > NI - 1) ihi = NI - 1;
        float wsum = 0.f;
        for (int i = ilo; i <= ihi; ++i)
            wsum += fmaxf(0.f, 1.f - fabsf(sf - (float)i) / ksc);
        int jlo = ilo - KPAD; if (jlo < 0) jlo = 0;
        int jhi = ihi + KPAD; if (jhi > NI - 1) jhi = NI - 1;
        wstart[row] = jlo;
        for (int k = 0; k < MT; ++k) {
            int j = jlo + k;
            float cw = 0.f;
            if (j <= jhi) {
                for (int tt = 0; tt < KS; ++tt) {
                    int i = j + KPAD - tt;   // blurred index feeding img[j]
                    if (i >= ilo && i <= ihi) {
                        float w = fmaxf(0.f, 1.f - fabsf(sf - (float)i) / ksc) / wsum;
                        cw += g[ax * KS + tt] * w;
                    }
                }
            }
            wtab[row * MT + k] = cw;
        }
    }
}

// ---------------------------------------------------------------------------
// Pass A: for each (b, i1) slab [160,160,3], contract dims 2 (->o2) and 3
// (->o3) with the banded composite weights. Output S[b][i1][43][43][3].
// ---------------------------------------------------------------------------
__global__ __launch_bounds__(256) void k_passA(
        const float* __restrict__ img, const float* __restrict__ wtab,
        const int* __restrict__ wstart, float* __restrict__ S) {
    __shared__ float rows[CH * NI * NC];        // 3840 f
    __shared__ float T[CH * NO * NC];           // 1032 f
    __shared__ float acc[NO * NO * NC];         // 5547 f
    __shared__ float w2[NO * MT], w3[NO * MT];  // 688 f each
    __shared__ int   s2[NO], s3[NO];
    int t = threadIdx.x;
    int blk = blockIdx.x;                        // b*160 + i1
    const float* src = img + (size_t)blk * (NI * NI * NC);

    for (int k = t; k < NO * MT; k += 256) {
        w2[k] = wtab[NO * MT + k];
        w3[k] = wtab[2 * NO * MT + k];
    }
    for (int k = t; k < NO; k += 256) { s2[k] = wstart[NO + k]; s3[k] = wstart[2 * NO + k]; }
    for (int k = t; k < NO * NO * NC; k += 256) acc[k] = 0.f;
    __syncthreads();

    for (int chunk = 0; chunk < NI / CH; ++chunk) {
        // stage CH rows (coalesced float4)
        const float4* csrc = (const float4*)(src + (size_t)chunk * CH * NI * NC);
        for (int k = t; k < CH * NI * NC / 4; k += 256)
            ((float4*)rows)[k] = csrc[k];
        __syncthreads();

        // contract i3 -> o3 : T[ch][o3][c]
        for (int task = t; task < CH * NO; task += 256) {
            int ch = task / NO, o3 = task % NO;
            int st = s3[o3];
            const float* rp = rows + ch * NI * NC;
            float a0 = 0.f, a1 = 0.f, a2 = 0.f;
            #pragma unroll
            for (int k = 0; k < MT; ++k) {
                int j = st + k; j = (j < NI) ? j : (NI - 1);  // pad taps have w=0
                float w = w3[o3 * MT + k];
                a0 += w * rp[j * 3 + 0];
                a1 += w * rp[j * 3 + 1];
                a2 += w * rp[j * 3 + 2];
            }
            T[task * NC + 0] = a0;
            T[task * NC + 1] = a1;
            T[task * NC + 2] = a2;
        }
        __syncthreads();

        // accumulate i2 -> o2 : acc[o2][o3][c] += w2 * T
        int i2base = chunk * CH;
        for (int task = t; task < NO * NO; task += 256) {
            int o2 = task / NO, o3 = task % NO;
            int st = s2[o2];
            int k0 = i2base - st;        k0 = (k0 > 0) ? k0 : 0;
            int k1 = i2base + CH - st;   k1 = (k1 < MT) ? k1 : MT;
            if (k1 > k0) {
                float a0 = 0.f, a1 = 0.f, a2 = 0.f;
                for (int k = k0; k < k1; ++k) {
                    float w = w2[o2 * MT + k];
                    int ch = st + k - i2base;
                    a0 += w * T[(ch * NO + o3) * NC + 0];
                    a1 += w * T[(ch * NO + o3) * NC + 1];
                    a2 += w * T[(ch * NO + o3) * NC + 2];
                }
                acc[task * NC + 0] += a0;
                acc[task * NC + 1] += a1;
                acc[task * NC + 2] += a2;
            }
        }
        __syncthreads();
    }

    float* Sp = S + (size_t)blk * (NO * NO * NC);
    for (int k = t; k < NO * NO * NC; k += 256) Sp[k] = acc[k];
}

// ---------------------------------------------------------------------------
// Pass B: contract dim 1 (i1 -> o1). out[b][o1][o2][o3][c]
// ---------------------------------------------------------------------------
__global__ __launch_bounds__(256) void k_passB(
        const float* __restrict__ S, const float* __restrict__ wtab,
        const int* __restrict__ wstart, float* __restrict__ out) {
    int blk = blockIdx.x;            // b*43 + o1
    int b = blk / NO, o1 = blk % NO;
    __shared__ float w1[MT];
    __shared__ int s1v;
    if (threadIdx.x < MT) w1[threadIdx.x] = wtab[o1 * MT + threadIdx.x];
    if (threadIdx.x == 0) s1v = wstart[o1];
    __syncthreads();
    const float* Sb = S + (size_t)b * NI * (NO * NO * NC);
    float* ob = out + (size_t)blk * (NO * NO * NC);
    int st = s1v;
    for (int e = threadIdx.x; e < NO * NO * NC; e += 256) {
        float a = 0.f;
        #pragma unroll
        for (int k = 0; k < MT; ++k) {
            int i1 = st + k; i1 = (i1 < NI) ? i1 : (NI - 1);  // pad taps w=0
            a += w1[k] * Sb[(size_t)i1 * (NO * NO * NC) + e];
        }
        ob[e] = a;
    }
}

// ---------------------------------------------------------------------------
extern "C" void kernel_launch(void* const* d_in, const int* in_sizes, int n_in,
                              void* d_out, int out_size, void* d_ws, size_t ws_size,
                              hipStream_t stream) {
    (void)in_sizes; (void)n_in; (void)out_size; (void)ws_size;
    const float* img  = (const float*)d_in[0];
    const float* kern = (const float*)d_in[1];
    float* out = (float*)d_out;

    char* ws = (char*)d_ws;
    float* wtab   = (float*)ws;                                  // 3*43*16 f
    int*   wstart = (int*)(ws + 3 * NO * MT * sizeof(float));    // 3*43 i32
    float* S      = (float*)(ws + 16384);                        // 14.2 MB

    k_setup<<<1, 256, 0, stream>>>(kern, wtab, wstart);
    k_passA<<<NB * NI, 256, 0, stream>>>(img, wtab, wstart, S);
    k_passB<<<NB * NO, 256, 0, stream>>>(S, wtab, wstart, out);
}

// Round 2
// 116.014 us; speedup vs baseline: 1.3656x; 1.3656x over previous
//
#include <hip/hip_runtime.h>

// Problem constants
#define NB 4      // batch
#define NI 160    // input spatial size (all 3 dims)
#define NO 43     // output spatial size: ceil(160/4)+3
#define NC 3      // channels
#define KS 7      // gaussian kernel size per axis
#define KPAD 3    // (KS-1)/2
#define MT 16     // max stored taps per composite-weight row (true max = 14)
#define CH 8      // i2 rows per chunk in fused fallback pass A
#define R1 8      // rows per block in k_A1

#define COLS (NO * NC)           // 129
#define SLICE (NO * NO * NC)     // 5547
#define A1_ELEMS ((size_t)NB * NI * NI * COLS)      // 13,209,600
#define S_ELEMS  ((size_t)NB * NI * SLICE)          // 3,550,080
#define OUT_ELEMS ((size_t)NB * NO * SLICE)         // 954,084

// ---------------------------------------------------------------------------
// Setup: factor 3D gaussian into per-axis marginals, compose with the
// jax.image.resize (antialias=True, 'linear') triangle weights into a banded
// 43x160 matrix per axis (<=14 taps, stored as 16 with zero pad).
// ---------------------------------------------------------------------------
__global__ void k_setup(const float* __restrict__ kern,
                        float* __restrict__ wtab, int* __restrict__ wstart) {
    __shared__ float g[3 * KS];
    int t = threadIdx.x;
    if (t < 3 * KS) {
        int ax = t / KS, idx = t % KS;
        float s = 0.f;
        for (int a = 0; a < KS; ++a)
            for (int b = 0; b < KS; ++b) {
                int i0 = (ax == 0) ? idx : a;
                int i1 = (ax == 1) ? idx : ((ax == 0) ? a : b);
                int i2 = (ax == 2) ? idx : b;
                s += kern[(i0 * KS + i1) * KS + i2];
            }
        g[t] = s;
    }
    __syncthreads();

    const float inv_scale = (float)NI / (float)NO;   // 160/43
    const float ksc = inv_scale;                     // kernel_scale (antialias)
    for (int row = t; row < 3 * NO; row += blockDim.x) {
        int ax = row / NO, o = row % NO;
        float sf = ((float)o + 0.5f) * inv_scale - 0.5f;   // half-pixel centers
        int ilo = (int)ceilf(sf - ksc);  if (ilo < 0) ilo = 0;
        int ihi = (int)floorf(sf + ksc); if (ihi > NI - 1) ihi = NI - 1;
        float wsum = 0.f;
        for (int i = ilo; i <= ihi; ++i)
            wsum += fmaxf(0.f, 1.f - fabsf(sf - (float)i) / ksc);
        int jlo = ilo - KPAD; if (jlo < 0) jlo = 0;
        int jhi = ihi + KPAD; if (jhi > NI - 1) jhi = NI - 1;
        wstart[row] = jlo;
        for (int k = 0; k < MT; ++k) {
            int j = jlo + k;
            float cw = 0.f;
            if (j <= jhi) {
                for (int tt = 0; tt < KS; ++tt) {
                    int i = j + KPAD - tt;   // blurred index feeding img[j]
                    if (i >= ilo && i <= ihi) {
                        float w = fmaxf(0.f, 1.f - fabsf(sf - (float)i) / ksc) / wsum;
                        cw += g[ax * KS + tt] * w;
                    }
                }
            }
            wtab[row * MT + k] = cw;
        }
    }
}

// ---------------------------------------------------------------------------
// FAST PATH pass 1: contract i3 -> o3.  A1[b][i1][i2][o3][c]
// Block = 256 thr handles R1=8 globally-contiguous rows of 160x3 floats.
// ---------------------------------------------------------------------------
__global__ __launch_bounds__(256) void k_A1(
        const float* __restrict__ img, const float* __restrict__ wtab,
        const int* __restrict__ wstart, float* __restrict__ A1) {
    __shared__ float rows[R1 * NI * NC];   // 3840 f = 15.4 KB
    __shared__ float w3[NO * MT];
    __shared__ int   s3[NO];
    int t = threadIdx.x;
    int blk = blockIdx.x;

    for (int k = t; k < NO * MT; k += 256) w3[k] = wtab[2 * NO * MT + k];
    for (int k = t; k < NO; k += 256) s3[k] = wstart[2 * NO + k];

    const float4* csrc = (const float4*)(img + (size_t)blk * (R1 * NI * NC));
    for (int k = t; k < R1 * NI * NC / 4; k += 256)
        ((float4*)rows)[k] = csrc[k];
    __syncthreads();

    float* dst = A1 + (size_t)blk * (R1 * COLS);
    for (int task = t; task < R1 * COLS; task += 256) {
        int row = task / COLS, o = task % COLS;
        int o3 = o / NC, c = o % NC;
        int st = s3[o3];
        const float* rp = rows + row * (NI * NC);
        float a = 0.f;
        #pragma unroll
        for (int k = 0; k < MT; ++k) {
            int j = st + k; j = (j < NI) ? j : (NI - 1);   // pad taps have w=0
            a += w3[o3 * MT + k] * rp[j * NC + c];
        }
        dst[task] = a;
    }
}

// ---------------------------------------------------------------------------
// FAST PATH pass 2: contract i2 -> o2.  S[b][i1][o2][o3][c]
// One thread per output element; reads coalesced per tap.
// ---------------------------------------------------------------------------
__global__ __launch_bounds__(256) void k_A2(
        const float* __restrict__ A1, const float* __restrict__ wtab,
        const int* __restrict__ wstart, float* __restrict__ S) {
    size_t idx = (size_t)blockIdx.x * 256 + threadIdx.x;
    if (idx >= S_ELEMS) return;
    int r    = (int)(idx % SLICE);
    int o2   = r / COLS;
    int col  = r % COLS;
    int slab = (int)(idx / SLICE);     // b*160 + i1
    int st = wstart[NO + o2];
    const float* wrow = wtab + (NO + o2) * MT;
    const float* base = A1 + (size_t)slab * (NI * COLS) + col;
    float a = 0.f;
    #pragma unroll
    for (int k = 0; k < MT; ++k) {
        int j = st + k; j = (j < NI) ? j : (NI - 1);
        a += wrow[k] * base[(size_t)j * COLS];
    }
    S[idx] = a;
}

// ---------------------------------------------------------------------------
// FAST PATH pass 3: contract i1 -> o1.  out[b][o1][o2][o3][c]
// ---------------------------------------------------------------------------
__global__ __launch_bounds__(256) void k_B(
        const float* __restrict__ S, const float* __restrict__ wtab,
        const int* __restrict__ wstart, float* __restrict__ out) {
    size_t idx = (size_t)blockIdx.x * 256 + threadIdx.x;
    if (idx >= OUT_ELEMS) return;
    int r  = (int)(idx % SLICE);
    int o1 = (int)((idx / SLICE) % NO);
    int b  = (int)(idx / ((size_t)NO * SLICE));
    int st = wstart[o1];
    const float* wrow = wtab + o1 * MT;
    const float* base = S + (size_t)b * NI * SLICE + r;
    float a = 0.f;
    #pragma unroll
    for (int k = 0; k < MT; ++k) {
        int j = st + k; j = (j < NI) ? j : (NI - 1);
        a += wrow[k] * base[(size_t)j * SLICE];
    }
    out[idx] = a;
}

// ---------------------------------------------------------------------------
// FALLBACK (round-1, known-correct) fused pass A + pass B — used only if
// ws_size is too small for the A1 intermediate.
// ---------------------------------------------------------------------------
__global__ __launch_bounds__(256) void k_passA(
        const float* __restrict__ img, const float* __restrict__ wtab,
        const int* __restrict__ wstart, float* __restrict__ S) {
    __shared__ float rows[CH * NI * NC];
    __shared__ float T[CH * NO * NC];
    __shared__ float acc[NO * NO * NC];
    __shared__ float w2[NO * MT], w3[NO * MT];
    __shared__ int   s2[NO], s3[NO];
    int t = threadIdx.x;
    int blk = blockIdx.x;
    const float* src = img + (size_t)blk * (NI * NI * NC);

    for (int k = t; k < NO * MT; k += 256) {
        w2[k] = wtab[NO * MT + k];
        w3[k] = wtab[2 * NO * MT + k];
    }
    for (int k = t; k < NO; k += 256) { s2[k] = wstart[NO + k]; s3[k] = wstart[2 * NO + k]; }
    for (int k = t; k < NO * NO * NC; k += 256) acc[k] = 0.f;
    __syncthreads();

    for (int chunk = 0; chunk < NI / CH; ++chunk) {
        const float4* csrc = (const float4*)(src + (size_t)chunk * CH * NI * NC);
        for (int k = t; k < CH * NI * NC / 4; k += 256)
            ((float4*)rows)[k] = csrc[k];
        __syncthreads();

        for (int task = t; task < CH * NO; task += 256) {
            int ch = task / NO, o3 = task % NO;
            int st = s3[o3];
            const float* rp = rows + ch * NI * NC;
            float a0 = 0.f, a1 = 0.f, a2 = 0.f;
            #pragma unroll
            for (int k = 0; k < MT; ++k) {
                int j = st + k; j = (j < NI) ? j : (NI - 1);
                float w = w3[o3 * MT + k];
                a0 += w * rp[j * 3 + 0];
                a1 += w * rp[j * 3 + 1];
                a2 += w * rp[j * 3 + 2];
            }
            T[task * NC + 0] = a0;
            T[task * NC + 1] = a1;
            T[task * NC + 2] = a2;
        }
        __syncthreads();

        int i2base = chunk * CH;
        for (int task = t; task < NO * NO; task += 256) {
            int o2 = task / NO, o3 = task % NO;
            int st = s2[o2];
            int k0 = i2base - st;        k0 = (k0 > 0) ? k0 : 0;
            int k1 = i2base + CH - st;   k1 = (k1 < MT) ? k1 : MT;
            if (k1 > k0) {
                float a0 = 0.f, a1 = 0.f, a2 = 0.f;
                for (int k = k0; k < k1; ++k) {
                    float w = w2[o2 * MT + k];
                    int ch = st + k - i2base;
                    a0 += w * T[(ch * NO + o3) * NC + 0];
                    a1 += w * T[(ch * NO + o3) * NC + 1];
                    a2 += w * T[(ch * NO + o3) * NC + 2];
                }
                acc[task * NC + 0] += a0;
                acc[task * NC + 1] += a1;
                acc[task * NC + 2] += a2;
            }
        }
        __syncthreads();
    }

    float* Sp = S + (size_t)blk * (NO * NO * NC);
    for (int k = t; k < NO * NO * NC; k += 256) Sp[k] = acc[k];
}

__global__ __launch_bounds__(256) void k_passB(
        const float* __restrict__ S, const float* __restrict__ wtab,
        const int* __restrict__ wstart, float* __restrict__ out) {
    int blk = blockIdx.x;
    int b = blk / NO, o1 = blk % NO;
    __shared__ float w1[MT];
    __shared__ int s1v;
    if (threadIdx.x < MT) w1[threadIdx.x] = wtab[o1 * MT + threadIdx.x];
    if (threadIdx.x == 0) s1v = wstart[o1];
    __syncthreads();
    const float* Sb = S + (size_t)b * NI * (NO * NO * NC);
    float* ob = out + (size_t)blk * (NO * NO * NC);
    int st = s1v;
    for (int e = threadIdx.x; e < NO * NO * NC; e += 256) {
        float a = 0.f;
        #pragma unroll
        for (int k = 0; k < MT; ++k) {
            int i1 = st + k; i1 = (i1 < NI) ? i1 : (NI - 1);
            a += w1[k] * Sb[(size_t)i1 * (NO * NO * NC) + e];
        }
        ob[e] = a;
    }
}

// ---------------------------------------------------------------------------
extern "C" void kernel_launch(void* const* d_in, const int* in_sizes, int n_in,
                              void* d_out, int out_size, void* d_ws, size_t ws_size,
                              hipStream_t stream) {
    (void)in_sizes; (void)n_in; (void)out_size;
    const float* img  = (const float*)d_in[0];
    const float* kern = (const float*)d_in[1];
    float* out = (float*)d_out;

    char* ws = (char*)d_ws;
    float* wtab   = (float*)ws;                                  // 3*43*16 f
    int*   wstart = (int*)(ws + 3 * NO * MT * sizeof(float));    // 3*43 i32

    const size_t TAB = 16384;
    const size_t A1_BYTES = A1_ELEMS * sizeof(float);            // 52.8 MB
    const size_t S_BYTES  = S_ELEMS * sizeof(float);             // 14.2 MB

    k_setup<<<1, 256, 0, stream>>>(kern, wtab, wstart);

    if (ws_size >= TAB + A1_BYTES + S_BYTES) {
        // fast streaming path
        float* A1 = (float*)(ws + TAB);
        float* S  = (float*)(ws + TAB + A1_BYTES);
        int nrow_blocks = (NB * NI * NI) / R1;                   // 12800
        k_A1<<<nrow_blocks, 256, 0, stream>>>(img, wtab, wstart, A1);
        int a2_blocks = (int)((S_ELEMS + 255) / 256);
        k_A2<<<a2_blocks, 256, 0, stream>>>(A1, wtab, wstart, S);
        int b_blocks = (int)((OUT_ELEMS + 255) / 256);
        k_B<<<b_blocks, 256, 0, stream>>>(S, wtab, wstart, out);
    } else {
        // fallback fused path (round-1)
        float* S = (float*)(ws + TAB);
        k_passA<<<NB * NI, 256, 0, stream>>>(img, wtab, wstart, S);
        k_passB<<<NB * NO, 256, 0, stream>>>(S, wtab, wstart, out);
    }
}